// Round 16
// baseline (160.184 us; speedup 1.0000x reference)
//
#include <hip/hip_runtime.h>
#include <math.h>
#include <stdint.h>

#define BB 2
#define CC 2048
#define DD 1024
#define HH 16
#define DHH 64
#define HALF 32

typedef __attribute__((ext_vector_type(8))) short bf16x8;
typedef __attribute__((ext_vector_type(4))) float f32x4;
typedef unsigned int u32;

#define EXPC 0.1803368801f   // 1/(8*ln2)

__device__ __forceinline__ ushort f2bf(float f) {
    uint32_t u = __builtin_bit_cast(uint32_t, f);
    u = (u + 0x7FFFu + ((u >> 16) & 1u)) >> 16;
    return (ushort)u;
}

// async global->LDS, 16B per lane; LDS dest = base(wave-uniform) + lane*16
__device__ __forceinline__ void gload16(const void* g, void* lds) {
    __builtin_amdgcn_global_load_lds(
        (const u32 __attribute__((address_space(1)))*)g,
        (u32 __attribute__((address_space(3)))*)lds, 16, 0, 0);
}

// ---------------- fused fp32->bf16 cast (x, w_qkv, w_out) + RoPE table ----------------
__global__ __launch_bounds__(256) void cast3_rope_k(const float* __restrict__ x,
                                                    const float* __restrict__ wq,
                                                    const float* __restrict__ wo,
                                                    ushort* __restrict__ xb,
                                                    ushort* __restrict__ wqb,
                                                    ushort* __restrict__ wob,
                                                    float* __restrict__ ct,
                                                    float* __restrict__ st) {
    if (blockIdx.x >= 4096) {
        int idx = (blockIdx.x - 4096) * 256 + threadIdx.x;   // 65536 tasks
        int m = idx >> 5;
        int t = idx & 31;
        double theta_d = pow(10000.0, -2.0 * ((double)t - 1.0) / 64.0);
        float theta = (float)theta_d;
        float ang = (float)m * theta;
        ct[idx] = cosf(ang);
        st[idx] = sinf(ang);
        return;
    }
    int id = blockIdx.x * 256 + threadIdx.x;   // 1,048,576 tasks of 8 elems
    const float* s;
    ushort* d;
    int off;
    if (id < 524288)       { s = x;  d = xb;  off = id; }
    else if (id < 917504)  { s = wq; d = wqb; off = id - 524288; }
    else                   { s = wo; d = wob; off = id - 917504; }
    float4 a = *reinterpret_cast<const float4*>(s + (size_t)off * 8);
    float4 b = *reinterpret_cast<const float4*>(s + (size_t)off * 8 + 4);
    bf16x8 o;
    o[0] = (short)f2bf(a.x); o[1] = (short)f2bf(a.y);
    o[2] = (short)f2bf(a.z); o[3] = (short)f2bf(a.w);
    o[4] = (short)f2bf(b.x); o[5] = (short)f2bf(b.y);
    o[6] = (short)f2bf(b.z); o[7] = (short)f2bf(b.w);
    *reinterpret_cast<bf16x8*>(d + (size_t)off * 8) = o;
}

// ---------------- QKV GEMM (bf16 MFMA) + fused RoPE rotation ----------------
// q,k,qr,kr row-major [B,H,C,64]; v tiled-transposed vT3[bh][kt=32][64 d][64 k]
__global__ __launch_bounds__(256) void qkv_gemm_mfma_k(const ushort* __restrict__ xb,
                                                       const ushort* __restrict__ wqb,
                                                       const float* __restrict__ ct,
                                                       const float* __restrict__ st,
                                                       ushort* __restrict__ q,
                                                       ushort* __restrict__ k,
                                                       ushort* __restrict__ qr,
                                                       ushort* __restrict__ kr,
                                                       ushort* __restrict__ vT3) {
    __shared__ ushort Al[128 * 64];
    __shared__ ushort Bl[128 * 64];
    const int tid = threadIdx.x;
    const int w = tid >> 6, l = tid & 63;
    const int l15 = l & 15, lg = l >> 4;
    const int wr = w >> 1, wc = w & 1;
    const int m0 = blockIdx.x * 128, n0 = blockIdx.y * 128;
    const int lrow = l >> 3, lch = l & 7;

    f32x4 acc[4][4];
#pragma unroll
    for (int i = 0; i < 4; i++)
#pragma unroll
        for (int j = 0; j < 4; j++) acc[i][j] = (f32x4){0.f, 0.f, 0.f, 0.f};

    for (int k0 = 0; k0 < 1024; k0 += 64) {
        __syncthreads();
#pragma unroll
        for (int c = 0; c < 4; c++) {
            int row = w * 32 + c * 8 + lrow;
            int gch = (lch ^ (row & 7)) * 8;
            gload16(xb + (size_t)(m0 + row) * 1024 + k0 + gch, &Al[(w * 32 + c * 8) * 64]);
            gload16(wqb + (size_t)(n0 + row) * 1024 + k0 + gch, &Bl[(w * 32 + c * 8) * 64]);
        }
        __syncthreads();
#pragma unroll
        for (int kk = 0; kk < 2; kk++) {
            bf16x8 a[4], b[4];
#pragma unroll
            for (int mt = 0; mt < 4; mt++) {
                int row = wr * 64 + mt * 16 + l15;
                a[mt] = *reinterpret_cast<const bf16x8*>(&Al[row * 64 + ((kk * 4 + lg) ^ (row & 7)) * 8]);
            }
#pragma unroll
            for (int nt = 0; nt < 4; nt++) {
                int row = wc * 64 + nt * 16 + l15;
                b[nt] = *reinterpret_cast<const bf16x8*>(&Bl[row * 64 + ((kk * 4 + lg) ^ (row & 7)) * 8]);
            }
#pragma unroll
            for (int mt = 0; mt < 4; mt++)
#pragma unroll
                for (int nt = 0; nt < 4; nt++)
                    acc[mt][nt] = __builtin_amdgcn_mfma_f32_16x16x32_bf16(a[mt], b[nt], acc[mt][nt], 0, 0, 0);
        }
    }
#pragma unroll
    for (int mt = 0; mt < 4; mt++)
#pragma unroll
        for (int nt = 0; nt < 4; nt++) {
            int n = n0 + wc * 64 + nt * 16 + l15;
            int part = n >> 10;          // wave-uniform
            int d = n & 1023;
            int h = d >> 6, dd = d & 63;
            int mbase = m0 + wr * 64 + mt * 16 + lg * 4;
            int bb = mbase >> 11, cpos = mbase & 2047;
            if (part == 2) {
                int kt = cpos >> 6, kcol = cpos & 63;
                ushort4 pk;
                pk.x = f2bf(acc[mt][nt][0]); pk.y = f2bf(acc[mt][nt][1]);
                pk.z = f2bf(acc[mt][nt][2]); pk.w = f2bf(acc[mt][nt][3]);
                size_t off = ((((size_t)(bb * HH + h)) * 32 + kt) * 64 + dd) * 64 + kcol;
                *reinterpret_cast<ushort4*>(vT3 + off) = pk;
            } else {
                ushort* dstu = (part == 0) ? q : k;
                ushort* dstr = (part == 0) ? qr : kr;
                const float sgn = (dd & 1) ? -1.f : 1.f;
                const int t = dd >> 1;
#pragma unroll
                for (int r = 0; r < 4; r++) {
                    float val = acc[mt][nt][r];
                    float par = __shfl_xor(val, 1, 64);   // pair partner (dd^1) in lane l15^1
                    float c = ct[(cpos + r) * 32 + t];
                    float s = st[(cpos + r) * 32 + t];
                    float rot = val * c + sgn * par * s;  // even: e*c+o*s ; odd: o*c-e*s
                    size_t base = (((size_t)bb * HH + h) * CC + (cpos + r)) * DHH + dd;
                    dstu[base] = f2bf(val);
                    dstr[base] = f2bf(rot);
                }
            }
        }
}

// ---------------- fused attention + denominator (paired-tile, merged A/B chains) ----------------
// Block = q-tiles (tp, 31-tp) of one bh. Uniform 32 iterations (BK=64).
// den shares ka reads A+B. NUM phase merged: one kra read pair feeds BOTH A and B
// num-MFMAs; SEPARATE PlA/PlB buffers remove the WAR serialization; PV-A and PV-B
// share vf registers. LDS 48 KB -> 2 blocks/CU (grid-capped anyway).
__global__ __launch_bounds__(256, 2) void attn_fused_k(const ushort* __restrict__ vT3,
                                                       const ushort* __restrict__ qg,
                                                       const ushort* __restrict__ kg,
                                                       const ushort* __restrict__ qrg,
                                                       const ushort* __restrict__ krg,
                                                       ushort* __restrict__ y) {
    __shared__ ushort Kl[2][64 * 64];    // 16 KB (unrotated K, dbuf)
    __shared__ ushort Krl[2][64 * 64];   // 16 KB (rotated K, dbuf)
    __shared__ ushort PlA[4][16 * 64];   // 8 KB per-wave P, tile A
    __shared__ ushort PlB[4][16 * 64];   // 8 KB per-wave P, tile B

    const int tid = threadIdx.x;
    const int w = tid >> 6, l = tid & 63;
    const int l15 = l & 15, lg = l >> 4;
    const int lrow = l >> 3, lch = l & 7;

    // XCD-pinned: bid&7 = XCD; 512 blocks total.
    const int bid = blockIdx.x;
    const int xcd = bid & 7;
    const int idx = bid >> 3;                 // 0..63
    const int sub = idx & 3;
    const int tp = idx >> 2;                  // 0..15
    const int bh = xcd * 4 + sub;
    const int NB = 31 - tp;
    const int q0a = tp * 64;
    const int q0b = NB * 64;

    const ushort* qb  = qg  + (size_t)bh * CC * DHH;
    const ushort* kb  = kg  + (size_t)bh * CC * DHH;
    const ushort* qrb = qrg + (size_t)bh * CC * DHH;
    const ushort* krb = krg + (size_t)bh * CC * DHH;
    const ushort* vtb = vT3 + (size_t)bh * 32 * 64 * 64;

    // Q fragments (MFMA B-operand) for both tiles, unrotated + rotated
    bf16x8 qfA[2], qfB[2], qrfA[2], qrfB[2];
#pragma unroll
    for (int kk = 0; kk < 2; kk++) {
        int ra = q0a + w * 16 + l15;
        int rb = q0b + w * 16 + l15;
        qfA[kk]  = *reinterpret_cast<const bf16x8*>(qb  + (size_t)ra * DHH + kk * 32 + lg * 8);
        qfB[kk]  = *reinterpret_cast<const bf16x8*>(qb  + (size_t)rb * DHH + kk * 32 + lg * 8);
        qrfA[kk] = *reinterpret_cast<const bf16x8*>(qrb + (size_t)ra * DHH + kk * 32 + lg * 8);
        qrfB[kk] = *reinterpret_cast<const bf16x8*>(qrb + (size_t)rb * DHH + kk * 32 + lg * 8);
    }

    f32x4 yaccA[4], yaccB[4];
#pragma unroll
    for (int nt = 0; nt < 4; nt++) {
        yaccA[nt] = (f32x4){0.f, 0.f, 0.f, 0.f};
        yaccB[nt] = (f32x4){0.f, 0.f, 0.f, 0.f};
    }
    float daccA0 = 0.f, daccA1 = 0.f, daccB0 = 0.f, daccB1 = 0.f;

#define STAGE(KT, BUF)                                                                         \
    {                                                                                          \
        const int sk0 = (KT) * 64;                                                             \
        _Pragma("unroll")                                                                      \
        for (int c = 0; c < 2; c++) {                                                          \
            int row = w * 16 + c * 8 + lrow;                                                   \
            int gch = (lch ^ (row & 7)) * 8;                                                   \
            gload16(kb + (size_t)(sk0 + row) * DHH + gch, &Kl[BUF][(w * 16 + c * 8) * 64]);    \
            if ((KT) <= NB)                                                                    \
                gload16(krb + (size_t)(sk0 + row) * DHH + gch, &Krl[BUF][(w * 16 + c * 8) * 64]); \
        }                                                                                      \
    }

    STAGE(0, 0);
    __syncthreads();   // tile 0 resident
    int cur = 0;

    for (int kt = 0; kt < 32; kt++) {
        const bool actA = (kt <= tp);
        const bool actB = (kt <= NB);   // actA implies actB
        const bool diagA = (kt == tp);
        const bool diagB = (kt == NB);

        // V fragments first: direct global->reg, 64B-coalesced; latency hides under den.
        bf16x8 vf[4][2];
        if (actB) {
            const ushort* vt0 = vtb + (size_t)kt * 64 * 64;
#pragma unroll
            for (int nt2 = 0; nt2 < 4; nt2++)
#pragma unroll
                for (int kk2 = 0; kk2 < 2; kk2++)
                    vf[nt2][kk2] = *reinterpret_cast<const bf16x8*>(
                        vt0 + (nt2 * 16 + l15) * 64 + kk2 * 32 + lg * 8);
        }

        if (kt + 1 < 32) STAGE(kt + 1, cur ^ 1);   // prefetch next tile

        // ---- denominator (both tiles, shared ka reads): S^T = mfma(K, Q) ----
#pragma unroll
        for (int nt = 0; nt < 4; nt++) {
            bf16x8 ka0, ka1;
            {
                int krow = nt * 16 + l15;
                ka0 = *reinterpret_cast<const bf16x8*>(&Kl[cur][krow * 64 + ((0 + lg) ^ (krow & 7)) * 8]);
                ka1 = *reinterpret_cast<const bf16x8*>(&Kl[cur][krow * 64 + ((4 + lg) ^ (krow & 7)) * 8]);
            }
            __builtin_amdgcn_s_setprio(1);
            f32x4 sA = (f32x4){0.f, 0.f, 0.f, 0.f};
            sA = __builtin_amdgcn_mfma_f32_16x16x32_bf16(ka0, qfA[0], sA, 0, 0, 0);
            sA = __builtin_amdgcn_mfma_f32_16x16x32_bf16(ka1, qfA[1], sA, 0, 0, 0);
            f32x4 sB = (f32x4){0.f, 0.f, 0.f, 0.f};
            sB = __builtin_amdgcn_mfma_f32_16x16x32_bf16(ka0, qfB[0], sB, 0, 0, 0);
            sB = __builtin_amdgcn_mfma_f32_16x16x32_bf16(ka1, qfB[1], sB, 0, 0, 0);
            __builtin_amdgcn_s_setprio(0);
            if (nt & 1) {
#pragma unroll
                for (int r = 0; r < 4; r++) {
                    daccA1 += __builtin_amdgcn_exp2f(sA[r] * EXPC);
                    daccB1 += __builtin_amdgcn_exp2f(sB[r] * EXPC);
                }
            } else {
#pragma unroll
                for (int r = 0; r < 4; r++) {
                    daccA0 += __builtin_amdgcn_exp2f(sA[r] * EXPC);
                    daccB0 += __builtin_amdgcn_exp2f(sB[r] * EXPC);
                }
            }
        }

        // ---- merged numerators: one kra read pair feeds BOTH A and B ----
        if (actB) {
            const int qrowA = q0a + w * 16 + l15;
            const int qrowB = q0b + w * 16 + l15;
#pragma unroll
            for (int nt = 0; nt < 4; nt++) {
                bf16x8 kra0, kra1;
                {
                    int krow = nt * 16 + l15;
                    kra0 = *reinterpret_cast<const bf16x8*>(&Krl[cur][krow * 64 + ((0 + lg) ^ (krow & 7)) * 8]);
                    kra1 = *reinterpret_cast<const bf16x8*>(&Krl[cur][krow * 64 + ((4 + lg) ^ (krow & 7)) * 8]);
                }
                __builtin_amdgcn_s_setprio(1);
                f32x4 sB2 = (f32x4){0.f, 0.f, 0.f, 0.f};
                sB2 = __builtin_amdgcn_mfma_f32_16x16x32_bf16(kra0, qrfB[0], sB2, 0, 0, 0);
                sB2 = __builtin_amdgcn_mfma_f32_16x16x32_bf16(kra1, qrfB[1], sB2, 0, 0, 0);
                f32x4 sA2 = (f32x4){0.f, 0.f, 0.f, 0.f};
                if (actA) {
                    sA2 = __builtin_amdgcn_mfma_f32_16x16x32_bf16(kra0, qrfA[0], sA2, 0, 0, 0);
                    sA2 = __builtin_amdgcn_mfma_f32_16x16x32_bf16(kra1, qrfA[1], sA2, 0, 0, 0);
                }
                __builtin_amdgcn_s_setprio(0);

                int swzc = (nt * 2 + (lg >> 1)) ^ (l15 & 7);
                float peB[4];
#pragma unroll
                for (int r = 0; r < 4; r++)
                    peB[r] = __builtin_amdgcn_exp2f(sB2[r] * EXPC);
                if (diagB) {
#pragma unroll
                    for (int r = 0; r < 4; r++) {
                        int key = kt * 64 + nt * 16 + lg * 4 + r;
                        peB[r] = (key <= qrowB) ? peB[r] : 0.f;
                    }
                }
                u32 pb0, pb1;
                asm("v_cvt_pk_bf16_f32 %0, %1, %2" : "=v"(pb0) : "v"(peB[0]), "v"(peB[1]));
                asm("v_cvt_pk_bf16_f32 %0, %1, %2" : "=v"(pb1) : "v"(peB[2]), "v"(peB[3]));
                uint2 prB; prB.x = pb0; prB.y = pb1;
                *reinterpret_cast<uint2*>(&PlB[w][l15 * 64 + swzc * 8 + (lg & 1) * 4]) = prB;

                if (actA) {
                    float peA[4];
#pragma unroll
                    for (int r = 0; r < 4; r++)
                        peA[r] = __builtin_amdgcn_exp2f(sA2[r] * EXPC);
                    if (diagA) {
#pragma unroll
                        for (int r = 0; r < 4; r++) {
                            int key = kt * 64 + nt * 16 + lg * 4 + r;
                            peA[r] = (key <= qrowA) ? peA[r] : 0.f;
                        }
                    }
                    u32 pa0, pa1;
                    asm("v_cvt_pk_bf16_f32 %0, %1, %2" : "=v"(pa0) : "v"(peA[0]), "v"(peA[1]));
                    asm("v_cvt_pk_bf16_f32 %0, %1, %2" : "=v"(pa1) : "v"(peA[2]), "v"(peA[3]));
                    uint2 prA; prA.x = pa0; prA.y = pa1;
                    *reinterpret_cast<uint2*>(&PlA[w][l15 * 64 + swzc * 8 + (lg & 1) * 4]) = prA;
                }
            }

            // ---- PV: A and B share vf; independent MFMA chains ----
            bf16x8 paB[2], paA[2];
#pragma unroll
            for (int kk2 = 0; kk2 < 2; kk2++) {
                int rc = (kk2 * 4 + lg) ^ (l15 & 7);
                paB[kk2] = *reinterpret_cast<const bf16x8*>(&PlB[w][l15 * 64 + rc * 8]);
                if (actA)
                    paA[kk2] = *reinterpret_cast<const bf16x8*>(&PlA[w][l15 * 64 + rc * 8]);
            }
            __builtin_amdgcn_s_setprio(1);
#pragma unroll
            for (int nt2 = 0; nt2 < 4; nt2++) {
                yaccB[nt2] = __builtin_amdgcn_mfma_f32_16x16x32_bf16(paB[0], vf[nt2][0], yaccB[nt2], 0, 0, 0);
                yaccB[nt2] = __builtin_amdgcn_mfma_f32_16x16x32_bf16(paB[1], vf[nt2][1], yaccB[nt2], 0, 0, 0);
                if (actA) {
                    yaccA[nt2] = __builtin_amdgcn_mfma_f32_16x16x32_bf16(paA[0], vf[nt2][0], yaccA[nt2], 0, 0, 0);
                    yaccA[nt2] = __builtin_amdgcn_mfma_f32_16x16x32_bf16(paA[1], vf[nt2][1], yaccA[nt2], 0, 0, 0);
                }
            }
            __builtin_amdgcn_s_setprio(0);
        }

        __syncthreads();   // next tile resident; buf[cur] reusable
        cur ^= 1;
    }

    // den reduction: lanes l15, +16, +32, +48 hold disjoint key subsets of q-row l15
    float denA = daccA0 + daccA1, denB = daccB0 + daccB1;
    denA += __shfl_xor(denA, 16, 64);
    denA += __shfl_xor(denA, 32, 64);
    denB += __shfl_xor(denB, 16, 64);
    denB += __shfl_xor(denB, 32, 64);

    const int b = bh >> 4, h = bh & 15;
#pragma unroll
    for (int r = 0; r < 4; r++) {
        float drA = __shfl(denA, lg * 4 + r, 64);   // den of q-row lg*4+r (within wave strip)
        float drB = __shfl(denB, lg * 4 + r, 64);
        float invA = 1.f / drA;
        float invB = 1.f / drB;
        int rowA = q0a + w * 16 + lg * 4 + r;
        int rowB = q0b + w * 16 + lg * 4 + r;
#pragma unroll
        for (int nt2 = 0; nt2 < 4; nt2++) {
            y[((size_t)b * CC + rowA) * DD + h * DHH + nt2 * 16 + l15] = f2bf(yaccA[nt2][r] * invA);
            y[((size_t)b * CC + rowB) * DD + h * DHH + nt2 * 16 + l15] = f2bf(yaccB[nt2][r] * invB);
        }
    }
#undef STAGE
}

// ---------------- output projection ----------------
__global__ __launch_bounds__(256) void out_proj_mfma_k(const ushort* __restrict__ yb,
                                                       const ushort* __restrict__ wob,
                                                       const float* __restrict__ bias,
                                                       float* __restrict__ out) {
    __shared__ ushort Al[128 * 64];
    __shared__ ushort Bl[128 * 64];
    const int tid = threadIdx.x;
    const int w = tid >> 6, l = tid & 63;
    const int l15 = l & 15, lg = l >> 4;
    const int wr = w >> 1, wc = w & 1;
    const int m0 = blockIdx.x * 128, n0 = blockIdx.y * 128;
    const int lrow = l >> 3, lch = l & 7;

    f32x4 acc[4][4];
#pragma unroll
    for (int i = 0; i < 4; i++)
#pragma unroll
        for (int j = 0; j < 4; j++) acc[i][j] = (f32x4){0.f, 0.f, 0.f, 0.f};

    for (int k0 = 0; k0 < 1024; k0 += 64) {
        __syncthreads();
#pragma unroll
        for (int c = 0; c < 4; c++) {
            int row = w * 32 + c * 8 + lrow;
            int gch = (lch ^ (row & 7)) * 8;
            gload16(yb + (size_t)(m0 + row) * 1024 + k0 + gch, &Al[(w * 32 + c * 8) * 64]);
            gload16(wob + (size_t)(n0 + row) * 1024 + k0 + gch, &Bl[(w * 32 + c * 8) * 64]);
        }
        __syncthreads();
#pragma unroll
        for (int kk = 0; kk < 2; kk++) {
            bf16x8 a[4], b[4];
#pragma unroll
            for (int mt = 0; mt < 4; mt++) {
                int row = wr * 64 + mt * 16 + l15;
                a[mt] = *reinterpret_cast<const bf16x8*>(&Al[row * 64 + ((kk * 4 + lg) ^ (row & 7)) * 8]);
            }
#pragma unroll
            for (int nt = 0; nt < 4; nt++) {
                int row = wc * 64 + nt * 16 + l15;
                b[nt] = *reinterpret_cast<const bf16x8*>(&Bl[row * 64 + ((kk * 4 + lg) ^ (row & 7)) * 8]);
            }
#pragma unroll
            for (int mt = 0; mt < 4; mt++)
#pragma unroll
                for (int nt = 0; nt < 4; nt++)
                    acc[mt][nt] = __builtin_amdgcn_mfma_f32_16x16x32_bf16(a[mt], b[nt], acc[mt][nt], 0, 0, 0);
        }
    }
#pragma unroll
    for (int mt = 0; mt < 4; mt++)
#pragma unroll
        for (int nt = 0; nt < 4; nt++) {
            int n = n0 + wc * 64 + nt * 16 + l15;
            float bv = bias[n];
#pragma unroll
            for (int r = 0; r < 4; r++) {
                int m = m0 + wr * 64 + mt * 16 + lg * 4 + r;
                out[(size_t)m * 1024 + n] = acc[mt][nt][r] + bv;
            }
        }
}

extern "C" void kernel_launch(void* const* d_in, const int* in_sizes, int n_in,
                              void* d_out, int out_size, void* d_ws, size_t ws_size,
                              hipStream_t stream) {
    (void)in_sizes; (void)n_in; (void)out_size; (void)ws_size;
    const float* x     = (const float*)d_in[0];
    const float* w_qkv = (const float*)d_in[1];
    const float* w_out = (const float*)d_in[2];
    const float* b_out = (const float*)d_in[3];
    float* out = (float*)d_out;

    char* p = (char*)d_ws;
    float* ct = (float*)p;  p += (size_t)CC * HALF * 4;
    float* st = (float*)p;  p += (size_t)CC * HALF * 4;
    ushort* xb  = (ushort*)p; p += (size_t)4096 * 1024 * 2;
    ushort* wqb = (ushort*)p; p += (size_t)3072 * 1024 * 2;
    ushort* wob = (ushort*)p; p += (size_t)1024 * 1024 * 2;
    const size_t TEN = (size_t)BB * HH * CC * DHH;  // 4,194,304
    ushort* qb = (ushort*)p; p += TEN * 2;
    ushort* kb = (ushort*)p; p += TEN * 2;
    ushort* vT = (ushort*)p; p += TEN * 2;
    ushort* qr = (ushort*)p; p += TEN * 2;
    ushort* kr = (ushort*)p; p += TEN * 2;
    ushort* yb = (ushort*)p; p += (size_t)4096 * 1024 * 2;

    cast3_rope_k<<<dim3(4352), dim3(256), 0, stream>>>(x, w_qkv, w_out, xb, wqb, wob, ct, st);
    qkv_gemm_mfma_k<<<dim3(32, 24), dim3(256), 0, stream>>>(xb, wqb, ct, st, qb, kb, qr, kr, vT);
    attn_fused_k<<<dim3(512), dim3(256), 0, stream>>>(vT, qb, kb, qr, kr, yb);
    out_proj_mfma_k<<<dim3(32, 8), dim3(256), 0, stream>>>(yb, wob, b_out, out);
}

// Round 17
// 152.568 us; speedup vs baseline: 1.0499x; 1.0499x over previous
//
#include <hip/hip_runtime.h>
#include <math.h>
#include <stdint.h>

#define BB 2
#define CC 2048
#define DD 1024
#define HH 16
#define DHH 64
#define HALF 32

typedef __attribute__((ext_vector_type(8))) short bf16x8;
typedef __attribute__((ext_vector_type(4))) float f32x4;
typedef unsigned int u32;

#define EXPC 0.1803368801f   // 1/(8*ln2) -- folded into q/qr at qkv epilogue

__device__ __forceinline__ ushort f2bf(float f) {
    uint32_t u = __builtin_bit_cast(uint32_t, f);
    u = (u + 0x7FFFu + ((u >> 16) & 1u)) >> 16;
    return (ushort)u;
}

// async global->LDS, 16B per lane; LDS dest = base(wave-uniform) + lane*16
__device__ __forceinline__ void gload16(const void* g, void* lds) {
    __builtin_amdgcn_global_load_lds(
        (const u32 __attribute__((address_space(1)))*)g,
        (u32 __attribute__((address_space(3)))*)lds, 16, 0, 0);
}

// ---------------- fused fp32->bf16 cast (x, w_qkv, w_out) + RoPE table ----------------
__global__ __launch_bounds__(256) void cast3_rope_k(const float* __restrict__ x,
                                                    const float* __restrict__ wq,
                                                    const float* __restrict__ wo,
                                                    ushort* __restrict__ xb,
                                                    ushort* __restrict__ wqb,
                                                    ushort* __restrict__ wob,
                                                    float* __restrict__ ct,
                                                    float* __restrict__ st) {
    if (blockIdx.x >= 4096) {
        int idx = (blockIdx.x - 4096) * 256 + threadIdx.x;   // 65536 tasks
        int m = idx >> 5;
        int t = idx & 31;
        double theta_d = pow(10000.0, -2.0 * ((double)t - 1.0) / 64.0);
        float theta = (float)theta_d;
        float ang = (float)m * theta;
        ct[idx] = cosf(ang);
        st[idx] = sinf(ang);
        return;
    }
    int id = blockIdx.x * 256 + threadIdx.x;   // 1,048,576 tasks of 8 elems
    const float* s;
    ushort* d;
    int off;
    if (id < 524288)       { s = x;  d = xb;  off = id; }
    else if (id < 917504)  { s = wq; d = wqb; off = id - 524288; }
    else                   { s = wo; d = wob; off = id - 917504; }
    float4 a = *reinterpret_cast<const float4*>(s + (size_t)off * 8);
    float4 b = *reinterpret_cast<const float4*>(s + (size_t)off * 8 + 4);
    bf16x8 o;
    o[0] = (short)f2bf(a.x); o[1] = (short)f2bf(a.y);
    o[2] = (short)f2bf(a.z); o[3] = (short)f2bf(a.w);
    o[4] = (short)f2bf(b.x); o[5] = (short)f2bf(b.y);
    o[6] = (short)f2bf(b.z); o[7] = (short)f2bf(b.w);
    *reinterpret_cast<bf16x8*>(d + (size_t)off * 8) = o;
}

// ---------------- QKV GEMM (bf16 MFMA) + fused RoPE rotation ----------------
// q,k,qr,kr row-major [B,H,C,64]; q/qr PRE-SCALED by EXPC (score-scale folded in);
// v tiled-transposed vT3[bh][kt64=32][64 d][64 k]
__global__ __launch_bounds__(256) void qkv_gemm_mfma_k(const ushort* __restrict__ xb,
                                                       const ushort* __restrict__ wqb,
                                                       const float* __restrict__ ct,
                                                       const float* __restrict__ st,
                                                       ushort* __restrict__ q,
                                                       ushort* __restrict__ k,
                                                       ushort* __restrict__ qr,
                                                       ushort* __restrict__ kr,
                                                       ushort* __restrict__ vT3) {
    __shared__ ushort Al[128 * 64];
    __shared__ ushort Bl[128 * 64];
    const int tid = threadIdx.x;
    const int w = tid >> 6, l = tid & 63;
    const int l15 = l & 15, lg = l >> 4;
    const int wr = w >> 1, wc = w & 1;
    const int m0 = blockIdx.x * 128, n0 = blockIdx.y * 128;
    const int lrow = l >> 3, lch = l & 7;

    f32x4 acc[4][4];
#pragma unroll
    for (int i = 0; i < 4; i++)
#pragma unroll
        for (int j = 0; j < 4; j++) acc[i][j] = (f32x4){0.f, 0.f, 0.f, 0.f};

    for (int k0 = 0; k0 < 1024; k0 += 64) {
        __syncthreads();
#pragma unroll
        for (int c = 0; c < 4; c++) {
            int row = w * 32 + c * 8 + lrow;
            int gch = (lch ^ (row & 7)) * 8;
            gload16(xb + (size_t)(m0 + row) * 1024 + k0 + gch, &Al[(w * 32 + c * 8) * 64]);
            gload16(wqb + (size_t)(n0 + row) * 1024 + k0 + gch, &Bl[(w * 32 + c * 8) * 64]);
        }
        __syncthreads();
#pragma unroll
        for (int kk = 0; kk < 2; kk++) {
            bf16x8 a[4], b[4];
#pragma unroll
            for (int mt = 0; mt < 4; mt++) {
                int row = wr * 64 + mt * 16 + l15;
                a[mt] = *reinterpret_cast<const bf16x8*>(&Al[row * 64 + ((kk * 4 + lg) ^ (row & 7)) * 8]);
            }
#pragma unroll
            for (int nt = 0; nt < 4; nt++) {
                int row = wc * 64 + nt * 16 + l15;
                b[nt] = *reinterpret_cast<const bf16x8*>(&Bl[row * 64 + ((kk * 4 + lg) ^ (row & 7)) * 8]);
            }
#pragma unroll
            for (int mt = 0; mt < 4; mt++)
#pragma unroll
                for (int nt = 0; nt < 4; nt++)
                    acc[mt][nt] = __builtin_amdgcn_mfma_f32_16x16x32_bf16(a[mt], b[nt], acc[mt][nt], 0, 0, 0);
        }
    }
#pragma unroll
    for (int mt = 0; mt < 4; mt++)
#pragma unroll
        for (int nt = 0; nt < 4; nt++) {
            int n = n0 + wc * 64 + nt * 16 + l15;
            int part = n >> 10;          // wave-uniform
            int d = n & 1023;
            int h = d >> 6, dd = d & 63;
            int mbase = m0 + wr * 64 + mt * 16 + lg * 4;
            int bb = mbase >> 11, cpos = mbase & 2047;
            if (part == 2) {
                int kt = cpos >> 6, kcol = cpos & 63;
                ushort4 pk;
                pk.x = f2bf(acc[mt][nt][0]); pk.y = f2bf(acc[mt][nt][1]);
                pk.z = f2bf(acc[mt][nt][2]); pk.w = f2bf(acc[mt][nt][3]);
                size_t off = ((((size_t)(bb * HH + h)) * 32 + kt) * 64 + dd) * 64 + kcol;
                *reinterpret_cast<ushort4*>(vT3 + off) = pk;
            } else {
                ushort* dstu = (part == 0) ? q : k;
                ushort* dstr = (part == 0) ? qr : kr;
                const float sc = (part == 0) ? EXPC : 1.f;   // fold score-scale into q side
                const float sgn = (dd & 1) ? -1.f : 1.f;
                const int t = dd >> 1;
#pragma unroll
                for (int r = 0; r < 4; r++) {
                    float val = acc[mt][nt][r];
                    float par = __shfl_xor(val, 1, 64);   // pair partner (dd^1) in lane l15^1
                    float c = ct[(cpos + r) * 32 + t];
                    float s = st[(cpos + r) * 32 + t];
                    float rot = val * c + sgn * par * s;  // even: e*c+o*s ; odd: o*c-e*s
                    size_t base = (((size_t)bb * HH + h) * CC + (cpos + r)) * DHH + dd;
                    dstu[base] = f2bf(val * sc);
                    dstr[base] = f2bf(rot * sc);
                }
            }
        }
}

// ---------------- fused attention + denominator (paired-tile, BK=128) ----------------
// Block = q-tiles (tp, 31-tp) of one bh. 16 iterations of 128-key tiles.
// den shares ka reads A+B; num/PV B-then-A through one per-wave P buffer [16][128].
// q/qr pre-scaled by EXPC -> exp2 directly on MFMA output (no per-score multiply).
// LDS 80 KB -> 2 blocks/CU (grid-capped anyway).
__global__ __launch_bounds__(256, 2) void attn_fused_k(const ushort* __restrict__ vT3,
                                                       const ushort* __restrict__ qg,
                                                       const ushort* __restrict__ kg,
                                                       const ushort* __restrict__ qrg,
                                                       const ushort* __restrict__ krg,
                                                       ushort* __restrict__ y) {
    __shared__ ushort Kl[2][128 * 64];    // 32 KB (unrotated K, dbuf)
    __shared__ ushort Krl[2][128 * 64];   // 32 KB (rotated K, dbuf)
    __shared__ ushort Pl[4][16 * 128];    // 16 KB per-wave P (tiles B then A)

    const int tid = threadIdx.x;
    const int w = tid >> 6, l = tid & 63;
    const int l15 = l & 15, lg = l >> 4;
    const int lrow = l >> 3, lch = l & 7;

    // XCD-pinned: bid&7 = XCD; 512 blocks total.
    const int bid = blockIdx.x;
    const int xcd = bid & 7;
    const int idx = bid >> 3;                 // 0..63
    const int sub = idx & 3;
    const int tp = idx >> 2;                  // 0..15
    const int bh = xcd * 4 + sub;
    const int NB = 31 - tp;
    const int q0a = tp * 64;
    const int q0b = NB * 64;
    const int lastA = (q0a + 63) >> 7;        // last 128-key tile needed by tile A
    const int lastB = (q0b + 63) >> 7;        // ... tile B (>= lastA)

    const ushort* qb  = qg  + (size_t)bh * CC * DHH;
    const ushort* kb  = kg  + (size_t)bh * CC * DHH;
    const ushort* qrb = qrg + (size_t)bh * CC * DHH;
    const ushort* krb = krg + (size_t)bh * CC * DHH;
    const ushort* vtb = vT3 + (size_t)bh * 32 * 64 * 64;

    // Q fragments (MFMA B-operand) for both tiles, unrotated + rotated
    bf16x8 qfA[2], qfB[2], qrfA[2], qrfB[2];
#pragma unroll
    for (int kk = 0; kk < 2; kk++) {
        int ra = q0a + w * 16 + l15;
        int rb = q0b + w * 16 + l15;
        qfA[kk]  = *reinterpret_cast<const bf16x8*>(qb  + (size_t)ra * DHH + kk * 32 + lg * 8);
        qfB[kk]  = *reinterpret_cast<const bf16x8*>(qb  + (size_t)rb * DHH + kk * 32 + lg * 8);
        qrfA[kk] = *reinterpret_cast<const bf16x8*>(qrb + (size_t)ra * DHH + kk * 32 + lg * 8);
        qrfB[kk] = *reinterpret_cast<const bf16x8*>(qrb + (size_t)rb * DHH + kk * 32 + lg * 8);
    }

    f32x4 yaccA[4], yaccB[4];
#pragma unroll
    for (int nt = 0; nt < 4; nt++) {
        yaccA[nt] = (f32x4){0.f, 0.f, 0.f, 0.f};
        yaccB[nt] = (f32x4){0.f, 0.f, 0.f, 0.f};
    }
    float daccA0 = 0.f, daccA1 = 0.f, daccB0 = 0.f, daccB1 = 0.f;

    // Stage 128 keys x 64 dh of K (always) and Kr (while needed)
#define STAGE(KT, BUF)                                                                         \
    {                                                                                          \
        const int sk0 = (KT) * 128;                                                            \
        _Pragma("unroll")                                                                      \
        for (int c = 0; c < 4; c++) {                                                          \
            int row = w * 32 + c * 8 + lrow;                                                   \
            int gch = (lch ^ (row & 7)) * 8;                                                   \
            gload16(kb + (size_t)(sk0 + row) * DHH + gch, &Kl[BUF][(w * 32 + c * 8) * 64]);    \
            if ((KT) <= lastB)                                                                 \
                gload16(krb + (size_t)(sk0 + row) * DHH + gch, &Krl[BUF][(w * 32 + c * 8) * 64]); \
        }                                                                                      \
    }

    // num(QRF, diag at LASTT)->Pl[w]->PV(into YACC); per-wave, no barrier.
#define NUMPV(Q0, QRF, YACC, LASTT)                                                            \
    {                                                                                          \
        const bool diag = (kt == (LASTT));                                                     \
        const int qrow = (Q0) + w * 16 + l15;                                                  \
        _Pragma("unroll")                                                                      \
        for (int nt = 0; nt < 8; nt++) {                                                       \
            bf16x8 kra0, kra1;                                                                 \
            {                                                                                  \
                int krow = nt * 16 + l15;                                                      \
                kra0 = *reinterpret_cast<const bf16x8*>(&Krl[cur][krow * 64 + ((0 + lg) ^ (krow & 7)) * 8]); \
                kra1 = *reinterpret_cast<const bf16x8*>(&Krl[cur][krow * 64 + ((4 + lg) ^ (krow & 7)) * 8]); \
            }                                                                                  \
            __builtin_amdgcn_s_setprio(1);                                                     \
            f32x4 s = (f32x4){0.f, 0.f, 0.f, 0.f};                                             \
            s = __builtin_amdgcn_mfma_f32_16x16x32_bf16(kra0, (QRF)[0], s, 0, 0, 0);           \
            s = __builtin_amdgcn_mfma_f32_16x16x32_bf16(kra1, (QRF)[1], s, 0, 0, 0);           \
            __builtin_amdgcn_s_setprio(0);                                                     \
            float pe[4];                                                                       \
            _Pragma("unroll")                                                                  \
            for (int r = 0; r < 4; r++)                                                        \
                pe[r] = __builtin_amdgcn_exp2f(s[r]);                                          \
            if (diag) {                                                                        \
                _Pragma("unroll")                                                              \
                for (int r = 0; r < 4; r++) {                                                  \
                    int key = kt * 128 + nt * 16 + lg * 4 + r;                                 \
                    pe[r] = (key <= qrow) ? pe[r] : 0.f;                                       \
                }                                                                              \
            }                                                                                  \
            u32 pk0, pk1;                                                                      \
            asm("v_cvt_pk_bf16_f32 %0, %1, %2" : "=v"(pk0) : "v"(pe[0]), "v"(pe[1]));          \
            asm("v_cvt_pk_bf16_f32 %0, %1, %2" : "=v"(pk1) : "v"(pe[2]), "v"(pe[3]));          \
            int swzc = (nt * 2 + (lg >> 1)) ^ (l15 & 7);                                       \
            uint2 pr; pr.x = pk0; pr.y = pk1;                                                  \
            *reinterpret_cast<uint2*>(&Pl[w][l15 * 128 + swzc * 8 + (lg & 1) * 4]) = pr;       \
        }                                                                                      \
        bf16x8 pa[4];                                                                          \
        _Pragma("unroll")                                                                      \
        for (int kk2 = 0; kk2 < 4; kk2++) {                                                    \
            int rc = (kk2 * 4 + lg) ^ (l15 & 7);                                               \
            pa[kk2] = *reinterpret_cast<const bf16x8*>(&Pl[w][l15 * 128 + rc * 8]);            \
        }                                                                                      \
        __builtin_amdgcn_s_setprio(1);                                                         \
        _Pragma("unroll")                                                                      \
        for (int nt2 = 0; nt2 < 4; nt2++) {                                                    \
            (YACC)[nt2] = __builtin_amdgcn_mfma_f32_16x16x32_bf16(pa[0], vf[nt2][0], (YACC)[nt2], 0, 0, 0); \
            (YACC)[nt2] = __builtin_amdgcn_mfma_f32_16x16x32_bf16(pa[1], vf[nt2][1], (YACC)[nt2], 0, 0, 0); \
            (YACC)[nt2] = __builtin_amdgcn_mfma_f32_16x16x32_bf16(pa[2], vf[nt2][2], (YACC)[nt2], 0, 0, 0); \
            (YACC)[nt2] = __builtin_amdgcn_mfma_f32_16x16x32_bf16(pa[3], vf[nt2][3], (YACC)[nt2], 0, 0, 0); \
        }                                                                                      \
        __builtin_amdgcn_s_setprio(0);                                                         \
    }

    STAGE(0, 0);
    __syncthreads();   // tile 0 resident
    int cur = 0;

    for (int kt = 0; kt < 16; kt++) {
        const bool actA = (kt <= lastA);
        const bool actB = (kt <= lastB);   // actA implies actB

        // V fragments first: direct global->reg from two 64-key vT3 tiles; hides under den.
        bf16x8 vf[4][4];
        if (actB) {
            const ushort* vt0 = vtb + (size_t)(2 * kt) * 64 * 64;
            const ushort* vt1 = vt0 + 64 * 64;
#pragma unroll
            for (int nt2 = 0; nt2 < 4; nt2++) {
                vf[nt2][0] = *reinterpret_cast<const bf16x8*>(vt0 + (nt2 * 16 + l15) * 64 + lg * 8);
                vf[nt2][1] = *reinterpret_cast<const bf16x8*>(vt0 + (nt2 * 16 + l15) * 64 + 32 + lg * 8);
                vf[nt2][2] = *reinterpret_cast<const bf16x8*>(vt1 + (nt2 * 16 + l15) * 64 + lg * 8);
                vf[nt2][3] = *reinterpret_cast<const bf16x8*>(vt1 + (nt2 * 16 + l15) * 64 + 32 + lg * 8);
            }
        }

        if (kt + 1 < 16) STAGE(kt + 1, cur ^ 1);   // prefetch next 128-key tile

        // ---- denominator (both tiles, shared ka reads): S^T = mfma(K, Q) ----
#pragma unroll
        for (int nt = 0; nt < 8; nt++) {
            bf16x8 ka0, ka1;
            {
                int krow = nt * 16 + l15;
                ka0 = *reinterpret_cast<const bf16x8*>(&Kl[cur][krow * 64 + ((0 + lg) ^ (krow & 7)) * 8]);
                ka1 = *reinterpret_cast<const bf16x8*>(&Kl[cur][krow * 64 + ((4 + lg) ^ (krow & 7)) * 8]);
            }
            __builtin_amdgcn_s_setprio(1);
            f32x4 sA = (f32x4){0.f, 0.f, 0.f, 0.f};
            sA = __builtin_amdgcn_mfma_f32_16x16x32_bf16(ka0, qfA[0], sA, 0, 0, 0);
            sA = __builtin_amdgcn_mfma_f32_16x16x32_bf16(ka1, qfA[1], sA, 0, 0, 0);
            f32x4 sB = (f32x4){0.f, 0.f, 0.f, 0.f};
            sB = __builtin_amdgcn_mfma_f32_16x16x32_bf16(ka0, qfB[0], sB, 0, 0, 0);
            sB = __builtin_amdgcn_mfma_f32_16x16x32_bf16(ka1, qfB[1], sB, 0, 0, 0);
            __builtin_amdgcn_s_setprio(0);
            if (nt & 1) {
#pragma unroll
                for (int r = 0; r < 4; r++) {
                    daccA1 += __builtin_amdgcn_exp2f(sA[r]);
                    daccB1 += __builtin_amdgcn_exp2f(sB[r]);
                }
            } else {
#pragma unroll
                for (int r = 0; r < 4; r++) {
                    daccA0 += __builtin_amdgcn_exp2f(sA[r]);
                    daccB0 += __builtin_amdgcn_exp2f(sB[r]);
                }
            }
        }

        // ---- numerator+PV: tile B, then tile A, through the single Pl buffer ----
        if (actB) NUMPV(q0b, qrfB, yaccB, lastB);
        if (actA) NUMPV(q0a, qrfA, yaccA, lastA);

        __syncthreads();   // next tile resident; buf[cur] reusable
        cur ^= 1;
    }

    // den reduction: lanes l15, +16, +32, +48 hold disjoint key subsets of q-row l15
    float denA = daccA0 + daccA1, denB = daccB0 + daccB1;
    denA += __shfl_xor(denA, 16, 64);
    denA += __shfl_xor(denA, 32, 64);
    denB += __shfl_xor(denB, 16, 64);
    denB += __shfl_xor(denB, 32, 64);

    const int b = bh >> 4, h = bh & 15;
#pragma unroll
    for (int r = 0; r < 4; r++) {
        float drA = __shfl(denA, lg * 4 + r, 64);   // den of q-row lg*4+r (within wave strip)
        float drB = __shfl(denB, lg * 4 + r, 64);
        float invA = 1.f / drA;
        float invB = 1.f / drB;
        int rowA = q0a + w * 16 + lg * 4 + r;
        int rowB = q0b + w * 16 + lg * 4 + r;
#pragma unroll
        for (int nt2 = 0; nt2 < 4; nt2++) {
            y[((size_t)b * CC + rowA) * DD + h * DHH + nt2 * 16 + l15] = f2bf(yaccA[nt2][r] * invA);
            y[((size_t)b * CC + rowB) * DD + h * DHH + nt2 * 16 + l15] = f2bf(yaccB[nt2][r] * invB);
        }
    }
#undef STAGE
#undef NUMPV
}

// ---------------- output projection ----------------
__global__ __launch_bounds__(256) void out_proj_mfma_k(const ushort* __restrict__ yb,
                                                       const ushort* __restrict__ wob,
                                                       const float* __restrict__ bias,
                                                       float* __restrict__ out) {
    __shared__ ushort Al[128 * 64];
    __shared__ ushort Bl[128 * 64];
    const int tid = threadIdx.x;
    const int w = tid >> 6, l = tid & 63;
    const int l15 = l & 15, lg = l >> 4;
    const int wr = w >> 1, wc = w & 1;
    const int m0 = blockIdx.x * 128, n0 = blockIdx.y * 128;
    const int lrow = l >> 3, lch = l & 7;

    f32x4 acc[4][4];
#pragma unroll
    for (int i = 0; i < 4; i++)
#pragma unroll
        for (int j = 0; j < 4; j++) acc[i][j] = (f32x4){0.f, 0.f, 0.f, 0.f};

    for (int k0 = 0; k0 < 1024; k0 += 64) {
        __syncthreads();
#pragma unroll
        for (int c = 0; c < 4; c++) {
            int row = w * 32 + c * 8 + lrow;
            int gch = (lch ^ (row & 7)) * 8;
            gload16(yb + (size_t)(m0 + row) * 1024 + k0 + gch, &Al[(w * 32 + c * 8) * 64]);
            gload16(wob + (size_t)(n0 + row) * 1024 + k0 + gch, &Bl[(w * 32 + c * 8) * 64]);
        }
        __syncthreads();
#pragma unroll
        for (int kk = 0; kk < 2; kk++) {
            bf16x8 a[4], b[4];
#pragma unroll
            for (int mt = 0; mt < 4; mt++) {
                int row = wr * 64 + mt * 16 + l15;
                a[mt] = *reinterpret_cast<const bf16x8*>(&Al[row * 64 + ((kk * 4 + lg) ^ (row & 7)) * 8]);
            }
#pragma unroll
            for (int nt = 0; nt < 4; nt++) {
                int row = wc * 64 + nt * 16 + l15;
                b[nt] = *reinterpret_cast<const bf16x8*>(&Bl[row * 64 + ((kk * 4 + lg) ^ (row & 7)) * 8]);
            }
#pragma unroll
            for (int mt = 0; mt < 4; mt++)
#pragma unroll
                for (int nt = 0; nt < 4; nt++)
                    acc[mt][nt] = __builtin_amdgcn_mfma_f32_16x16x32_bf16(a[mt], b[nt], acc[mt][nt], 0, 0, 0);
        }
    }
#pragma unroll
    for (int mt = 0; mt < 4; mt++)
#pragma unroll
        for (int nt = 0; nt < 4; nt++) {
            int n = n0 + wc * 64 + nt * 16 + l15;
            float bv = bias[n];
#pragma unroll
            for (int r = 0; r < 4; r++) {
                int m = m0 + wr * 64 + mt * 16 + lg * 4 + r;
                out[(size_t)m * 1024 + n] = acc[mt][nt][r] + bv;
            }
        }
}

extern "C" void kernel_launch(void* const* d_in, const int* in_sizes, int n_in,
                              void* d_out, int out_size, void* d_ws, size_t ws_size,
                              hipStream_t stream) {
    (void)in_sizes; (void)n_in; (void)out_size; (void)ws_size;
    const float* x     = (const float*)d_in[0];
    const float* w_qkv = (const float*)d_in[1];
    const float* w_out = (const float*)d_in[2];
    const float* b_out = (const float*)d_in[3];
    float* out = (float*)d_out;

    char* p = (char*)d_ws;
    float* ct = (float*)p;  p += (size_t)CC * HALF * 4;
    float* st = (float*)p;  p += (size_t)CC * HALF * 4;
    ushort* xb  = (ushort*)p; p += (size_t)4096 * 1024 * 2;
    ushort* wqb = (ushort*)p; p += (size_t)3072 * 1024 * 2;
    ushort* wob = (ushort*)p; p += (size_t)1024 * 1024 * 2;
    const size_t TEN = (size_t)BB * HH * CC * DHH;  // 4,194,304
    ushort* qb = (ushort*)p; p += TEN * 2;
    ushort* kb = (ushort*)p; p += TEN * 2;
    ushort* vT = (ushort*)p; p += TEN * 2;
    ushort* qr = (ushort*)p; p += TEN * 2;
    ushort* kr = (ushort*)p; p += TEN * 2;
    ushort* yb = (ushort*)p; p += (size_t)4096 * 1024 * 2;

    cast3_rope_k<<<dim3(4352), dim3(256), 0, stream>>>(x, w_qkv, w_out, xb, wqb, wob, ct, st);
    qkv_gemm_mfma_k<<<dim3(32, 24), dim3(256), 0, stream>>>(xb, wqb, ct, st, qb, kb, qr, kr, vT);
    attn_fused_k<<<dim3(512), dim3(256), 0, stream>>>(vT, qb, kb, qr, kr, yb);
    out_proj_mfma_k<<<dim3(32, 8), dim3(256), 0, stream>>>(yb, wob, b_out, out);
}

// Round 18
// 151.392 us; speedup vs baseline: 1.0581x; 1.0078x over previous
//
#include <hip/hip_runtime.h>
#include <math.h>
#include <stdint.h>

#define BB 2
#define CC 2048
#define DD 1024
#define HH 16
#define DHH 64
#define HALF 32

typedef __attribute__((ext_vector_type(8))) short bf16x8;
typedef __attribute__((ext_vector_type(4))) float f32x4;
typedef unsigned int u32;

#define EXPC 0.1803368801f   // 1/(8*ln2) -- folded into q/qr at qkv epilogue

__device__ __forceinline__ ushort f2bf(float f) {
    uint32_t u = __builtin_bit_cast(uint32_t, f);
    u = (u + 0x7FFFu + ((u >> 16) & 1u)) >> 16;
    return (ushort)u;
}

// async global->LDS, 16B per lane; LDS dest = base(wave-uniform) + lane*16
__device__ __forceinline__ void gload16(const void* g, void* lds) {
    __builtin_amdgcn_global_load_lds(
        (const u32 __attribute__((address_space(1)))*)g,
        (u32 __attribute__((address_space(3)))*)lds, 16, 0, 0);
}

// ---------------- fused fp32->bf16 cast (x, w_qkv, w_out) + RoPE table ----------------
__global__ __launch_bounds__(256) void cast3_rope_k(const float* __restrict__ x,
                                                    const float* __restrict__ wq,
                                                    const float* __restrict__ wo,
                                                    ushort* __restrict__ xb,
                                                    ushort* __restrict__ wqb,
                                                    ushort* __restrict__ wob,
                                                    float* __restrict__ ct,
                                                    float* __restrict__ st) {
    if (blockIdx.x >= 4096) {
        int idx = (blockIdx.x - 4096) * 256 + threadIdx.x;   // 65536 tasks
        int m = idx >> 5;
        int t = idx & 31;
        double theta_d = pow(10000.0, -2.0 * ((double)t - 1.0) / 64.0);
        float theta = (float)theta_d;
        float ang = (float)m * theta;
        ct[idx] = cosf(ang);
        st[idx] = sinf(ang);
        return;
    }
    int id = blockIdx.x * 256 + threadIdx.x;   // 1,048,576 tasks of 8 elems
    const float* s;
    ushort* d;
    int off;
    if (id < 524288)       { s = x;  d = xb;  off = id; }
    else if (id < 917504)  { s = wq; d = wqb; off = id - 524288; }
    else                   { s = wo; d = wob; off = id - 917504; }
    float4 a = *reinterpret_cast<const float4*>(s + (size_t)off * 8);
    float4 b = *reinterpret_cast<const float4*>(s + (size_t)off * 8 + 4);
    bf16x8 o;
    o[0] = (short)f2bf(a.x); o[1] = (short)f2bf(a.y);
    o[2] = (short)f2bf(a.z); o[3] = (short)f2bf(a.w);
    o[4] = (short)f2bf(b.x); o[5] = (short)f2bf(b.y);
    o[6] = (short)f2bf(b.z); o[7] = (short)f2bf(b.w);
    *reinterpret_cast<bf16x8*>(d + (size_t)off * 8) = o;
}

// ---------------- QKV GEMM (bf16 MFMA) + fused RoPE rotation ----------------
// q,k,qr,kr row-major [B,H,C,64]; q/qr PRE-SCALED by EXPC (score-scale folded in);
// v tiled-transposed vT3[bh][kt64=32][64 d][64 k]
__global__ __launch_bounds__(256) void qkv_gemm_mfma_k(const ushort* __restrict__ xb,
                                                       const ushort* __restrict__ wqb,
                                                       const float* __restrict__ ct,
                                                       const float* __restrict__ st,
                                                       ushort* __restrict__ q,
                                                       ushort* __restrict__ k,
                                                       ushort* __restrict__ qr,
                                                       ushort* __restrict__ kr,
                                                       ushort* __restrict__ vT3) {
    __shared__ ushort Al[128 * 64];
    __shared__ ushort Bl[128 * 64];
    const int tid = threadIdx.x;
    const int w = tid >> 6, l = tid & 63;
    const int l15 = l & 15, lg = l >> 4;
    const int wr = w >> 1, wc = w & 1;
    const int m0 = blockIdx.x * 128, n0 = blockIdx.y * 128;
    const int lrow = l >> 3, lch = l & 7;

    f32x4 acc[4][4];
#pragma unroll
    for (int i = 0; i < 4; i++)
#pragma unroll
        for (int j = 0; j < 4; j++) acc[i][j] = (f32x4){0.f, 0.f, 0.f, 0.f};

    for (int k0 = 0; k0 < 1024; k0 += 64) {
        __syncthreads();
#pragma unroll
        for (int c = 0; c < 4; c++) {
            int row = w * 32 + c * 8 + lrow;
            int gch = (lch ^ (row & 7)) * 8;
            gload16(xb + (size_t)(m0 + row) * 1024 + k0 + gch, &Al[(w * 32 + c * 8) * 64]);
            gload16(wqb + (size_t)(n0 + row) * 1024 + k0 + gch, &Bl[(w * 32 + c * 8) * 64]);
        }
        __syncthreads();
#pragma unroll
        for (int kk = 0; kk < 2; kk++) {
            bf16x8 a[4], b[4];
#pragma unroll
            for (int mt = 0; mt < 4; mt++) {
                int row = wr * 64 + mt * 16 + l15;
                a[mt] = *reinterpret_cast<const bf16x8*>(&Al[row * 64 + ((kk * 4 + lg) ^ (row & 7)) * 8]);
            }
#pragma unroll
            for (int nt = 0; nt < 4; nt++) {
                int row = wc * 64 + nt * 16 + l15;
                b[nt] = *reinterpret_cast<const bf16x8*>(&Bl[row * 64 + ((kk * 4 + lg) ^ (row & 7)) * 8]);
            }
#pragma unroll
            for (int mt = 0; mt < 4; mt++)
#pragma unroll
                for (int nt = 0; nt < 4; nt++)
                    acc[mt][nt] = __builtin_amdgcn_mfma_f32_16x16x32_bf16(a[mt], b[nt], acc[mt][nt], 0, 0, 0);
        }
    }
#pragma unroll
    for (int mt = 0; mt < 4; mt++)
#pragma unroll
        for (int nt = 0; nt < 4; nt++) {
            int n = n0 + wc * 64 + nt * 16 + l15;
            int part = n >> 10;          // wave-uniform
            int d = n & 1023;
            int h = d >> 6, dd = d & 63;
            int mbase = m0 + wr * 64 + mt * 16 + lg * 4;
            int bb = mbase >> 11, cpos = mbase & 2047;
            if (part == 2) {
                int kt = cpos >> 6, kcol = cpos & 63;
                ushort4 pk;
                pk.x = f2bf(acc[mt][nt][0]); pk.y = f2bf(acc[mt][nt][1]);
                pk.z = f2bf(acc[mt][nt][2]); pk.w = f2bf(acc[mt][nt][3]);
                size_t off = ((((size_t)(bb * HH + h)) * 32 + kt) * 64 + dd) * 64 + kcol;
                *reinterpret_cast<ushort4*>(vT3 + off) = pk;
            } else {
                ushort* dstu = (part == 0) ? q : k;
                ushort* dstr = (part == 0) ? qr : kr;
                const float sc = (part == 0) ? EXPC : 1.f;   // fold score-scale into q side
                const float sgn = (dd & 1) ? -1.f : 1.f;
                const int t = dd >> 1;
#pragma unroll
                for (int r = 0; r < 4; r++) {
                    float val = acc[mt][nt][r];
                    float par = __shfl_xor(val, 1, 64);   // pair partner (dd^1) in lane l15^1
                    float c = ct[(cpos + r) * 32 + t];
                    float s = st[(cpos + r) * 32 + t];
                    float rot = val * c + sgn * par * s;  // even: e*c+o*s ; odd: o*c-e*s
                    size_t base = (((size_t)bb * HH + h) * CC + (cpos + r)) * DHH + dd;
                    dstu[base] = f2bf(val * sc);
                    dstr[base] = f2bf(rot * sc);
                }
            }
        }
}

// ---------------- fused attention + denominator (paired-tile, BK=128, no setprio) ----------------
// Block = q-tiles (tp, 31-tp) of one bh. 16 iterations of 128-key tiles.
// den shares ka reads A+B; num/PV B-then-A through one per-wave P buffer [16][128].
// q/qr pre-scaled by EXPC -> exp2 directly on MFMA output. setprio REMOVED (m190:
// hurts barrier-synced lockstep waves). LDS 80 KB -> 2 blocks/CU (grid-capped).
__global__ __launch_bounds__(256, 2) void attn_fused_k(const ushort* __restrict__ vT3,
                                                       const ushort* __restrict__ qg,
                                                       const ushort* __restrict__ kg,
                                                       const ushort* __restrict__ qrg,
                                                       const ushort* __restrict__ krg,
                                                       ushort* __restrict__ y) {
    __shared__ ushort Kl[2][128 * 64];    // 32 KB (unrotated K, dbuf)
    __shared__ ushort Krl[2][128 * 64];   // 32 KB (rotated K, dbuf)
    __shared__ ushort Pl[4][16 * 128];    // 16 KB per-wave P (tiles B then A)

    const int tid = threadIdx.x;
    const int w = tid >> 6, l = tid & 63;
    const int l15 = l & 15, lg = l >> 4;
    const int lrow = l >> 3, lch = l & 7;

    // XCD-pinned: bid&7 = XCD; 512 blocks total.
    const int bid = blockIdx.x;
    const int xcd = bid & 7;
    const int idx = bid >> 3;                 // 0..63
    const int sub = idx & 3;
    const int tp = idx >> 2;                  // 0..15
    const int bh = xcd * 4 + sub;
    const int NB = 31 - tp;
    const int q0a = tp * 64;
    const int q0b = NB * 64;
    const int lastA = (q0a + 63) >> 7;        // last 128-key tile needed by tile A
    const int lastB = (q0b + 63) >> 7;        // ... tile B (>= lastA)

    const ushort* qb  = qg  + (size_t)bh * CC * DHH;
    const ushort* kb  = kg  + (size_t)bh * CC * DHH;
    const ushort* qrb = qrg + (size_t)bh * CC * DHH;
    const ushort* krb = krg + (size_t)bh * CC * DHH;
    const ushort* vtb = vT3 + (size_t)bh * 32 * 64 * 64;

    // Q fragments (MFMA B-operand) for both tiles, unrotated + rotated
    bf16x8 qfA[2], qfB[2], qrfA[2], qrfB[2];
#pragma unroll
    for (int kk = 0; kk < 2; kk++) {
        int ra = q0a + w * 16 + l15;
        int rb = q0b + w * 16 + l15;
        qfA[kk]  = *reinterpret_cast<const bf16x8*>(qb  + (size_t)ra * DHH + kk * 32 + lg * 8);
        qfB[kk]  = *reinterpret_cast<const bf16x8*>(qb  + (size_t)rb * DHH + kk * 32 + lg * 8);
        qrfA[kk] = *reinterpret_cast<const bf16x8*>(qrb + (size_t)ra * DHH + kk * 32 + lg * 8);
        qrfB[kk] = *reinterpret_cast<const bf16x8*>(qrb + (size_t)rb * DHH + kk * 32 + lg * 8);
    }

    f32x4 yaccA[4], yaccB[4];
#pragma unroll
    for (int nt = 0; nt < 4; nt++) {
        yaccA[nt] = (f32x4){0.f, 0.f, 0.f, 0.f};
        yaccB[nt] = (f32x4){0.f, 0.f, 0.f, 0.f};
    }
    float daccA0 = 0.f, daccA1 = 0.f, daccB0 = 0.f, daccB1 = 0.f;

    // Stage 128 keys x 64 dh of K (always) and Kr (while needed)
#define STAGE(KT, BUF)                                                                         \
    {                                                                                          \
        const int sk0 = (KT) * 128;                                                            \
        _Pragma("unroll")                                                                      \
        for (int c = 0; c < 4; c++) {                                                          \
            int row = w * 32 + c * 8 + lrow;                                                   \
            int gch = (lch ^ (row & 7)) * 8;                                                   \
            gload16(kb + (size_t)(sk0 + row) * DHH + gch, &Kl[BUF][(w * 32 + c * 8) * 64]);    \
            if ((KT) <= lastB)                                                                 \
                gload16(krb + (size_t)(sk0 + row) * DHH + gch, &Krl[BUF][(w * 32 + c * 8) * 64]); \
        }                                                                                      \
    }

    // num(QRF, diag at LASTT)->Pl[w]->PV(into YACC); per-wave, no barrier.
#define NUMPV(Q0, QRF, YACC, LASTT)                                                            \
    {                                                                                          \
        const bool diag = (kt == (LASTT));                                                     \
        const int qrow = (Q0) + w * 16 + l15;                                                  \
        _Pragma("unroll")                                                                      \
        for (int nt = 0; nt < 8; nt++) {                                                       \
            bf16x8 kra0, kra1;                                                                 \
            {                                                                                  \
                int krow = nt * 16 + l15;                                                      \
                kra0 = *reinterpret_cast<const bf16x8*>(&Krl[cur][krow * 64 + ((0 + lg) ^ (krow & 7)) * 8]); \
                kra1 = *reinterpret_cast<const bf16x8*>(&Krl[cur][krow * 64 + ((4 + lg) ^ (krow & 7)) * 8]); \
            }                                                                                  \
            f32x4 s = (f32x4){0.f, 0.f, 0.f, 0.f};                                             \
            s = __builtin_amdgcn_mfma_f32_16x16x32_bf16(kra0, (QRF)[0], s, 0, 0, 0);           \
            s = __builtin_amdgcn_mfma_f32_16x16x32_bf16(kra1, (QRF)[1], s, 0, 0, 0);           \
            float pe[4];                                                                       \
            _Pragma("unroll")                                                                  \
            for (int r = 0; r < 4; r++)                                                        \
                pe[r] = __builtin_amdgcn_exp2f(s[r]);                                          \
            if (diag) {                                                                        \
                _Pragma("unroll")                                                              \
                for (int r = 0; r < 4; r++) {                                                  \
                    int key = kt * 128 + nt * 16 + lg * 4 + r;                                 \
                    pe[r] = (key <= qrow) ? pe[r] : 0.f;                                       \
                }                                                                              \
            }                                                                                  \
            u32 pk0, pk1;                                                                      \
            asm("v_cvt_pk_bf16_f32 %0, %1, %2" : "=v"(pk0) : "v"(pe[0]), "v"(pe[1]));          \
            asm("v_cvt_pk_bf16_f32 %0, %1, %2" : "=v"(pk1) : "v"(pe[2]), "v"(pe[3]));          \
            int swzc = (nt * 2 + (lg >> 1)) ^ (l15 & 7);                                       \
            uint2 pr; pr.x = pk0; pr.y = pk1;                                                  \
            *reinterpret_cast<uint2*>(&Pl[w][l15 * 128 + swzc * 8 + (lg & 1) * 4]) = pr;       \
        }                                                                                      \
        bf16x8 pa[4];                                                                          \
        _Pragma("unroll")                                                                      \
        for (int kk2 = 0; kk2 < 4; kk2++) {                                                    \
            int rc = (kk2 * 4 + lg) ^ (l15 & 7);                                               \
            pa[kk2] = *reinterpret_cast<const bf16x8*>(&Pl[w][l15 * 128 + rc * 8]);            \
        }                                                                                      \
        _Pragma("unroll")                                                                      \
        for (int nt2 = 0; nt2 < 4; nt2++) {                                                    \
            (YACC)[nt2] = __builtin_amdgcn_mfma_f32_16x16x32_bf16(pa[0], vf[nt2][0], (YACC)[nt2], 0, 0, 0); \
            (YACC)[nt2] = __builtin_amdgcn_mfma_f32_16x16x32_bf16(pa[1], vf[nt2][1], (YACC)[nt2], 0, 0, 0); \
            (YACC)[nt2] = __builtin_amdgcn_mfma_f32_16x16x32_bf16(pa[2], vf[nt2][2], (YACC)[nt2], 0, 0, 0); \
            (YACC)[nt2] = __builtin_amdgcn_mfma_f32_16x16x32_bf16(pa[3], vf[nt2][3], (YACC)[nt2], 0, 0, 0); \
        }                                                                                      \
    }

    STAGE(0, 0);
    __syncthreads();   // tile 0 resident
    int cur = 0;

    for (int kt = 0; kt < 16; kt++) {
        const bool actA = (kt <= lastA);
        const bool actB = (kt <= lastB);   // actA implies actB

        // V fragments first: direct global->reg from two 64-key vT3 tiles; hides under den.
        bf16x8 vf[4][4];
        if (actB) {
            const ushort* vt0 = vtb + (size_t)(2 * kt) * 64 * 64;
            const ushort* vt1 = vt0 + 64 * 64;
#pragma unroll
            for (int nt2 = 0; nt2 < 4; nt2++) {
                vf[nt2][0] = *reinterpret_cast<const bf16x8*>(vt0 + (nt2 * 16 + l15) * 64 + lg * 8);
                vf[nt2][1] = *reinterpret_cast<const bf16x8*>(vt0 + (nt2 * 16 + l15) * 64 + 32 + lg * 8);
                vf[nt2][2] = *reinterpret_cast<const bf16x8*>(vt1 + (nt2 * 16 + l15) * 64 + lg * 8);
                vf[nt2][3] = *reinterpret_cast<const bf16x8*>(vt1 + (nt2 * 16 + l15) * 64 + 32 + lg * 8);
            }
        }

        if (kt + 1 < 16) STAGE(kt + 1, cur ^ 1);   // prefetch next 128-key tile

        // ---- denominator (both tiles, shared ka reads): S^T = mfma(K, Q) ----
#pragma unroll
        for (int nt = 0; nt < 8; nt++) {
            bf16x8 ka0, ka1;
            {
                int krow = nt * 16 + l15;
                ka0 = *reinterpret_cast<const bf16x8*>(&Kl[cur][krow * 64 + ((0 + lg) ^ (krow & 7)) * 8]);
                ka1 = *reinterpret_cast<const bf16x8*>(&Kl[cur][krow * 64 + ((4 + lg) ^ (krow & 7)) * 8]);
            }
            f32x4 sA = (f32x4){0.f, 0.f, 0.f, 0.f};
            sA = __builtin_amdgcn_mfma_f32_16x16x32_bf16(ka0, qfA[0], sA, 0, 0, 0);
            sA = __builtin_amdgcn_mfma_f32_16x16x32_bf16(ka1, qfA[1], sA, 0, 0, 0);
            f32x4 sB = (f32x4){0.f, 0.f, 0.f, 0.f};
            sB = __builtin_amdgcn_mfma_f32_16x16x32_bf16(ka0, qfB[0], sB, 0, 0, 0);
            sB = __builtin_amdgcn_mfma_f32_16x16x32_bf16(ka1, qfB[1], sB, 0, 0, 0);
            if (nt & 1) {
#pragma unroll
                for (int r = 0; r < 4; r++) {
                    daccA1 += __builtin_amdgcn_exp2f(sA[r]);
                    daccB1 += __builtin_amdgcn_exp2f(sB[r]);
                }
            } else {
#pragma unroll
                for (int r = 0; r < 4; r++) {
                    daccA0 += __builtin_amdgcn_exp2f(sA[r]);
                    daccB0 += __builtin_amdgcn_exp2f(sB[r]);
                }
            }
        }

        // ---- numerator+PV: tile B, then tile A, through the single Pl buffer ----
        if (actB) NUMPV(q0b, qrfB, yaccB, lastB);
        if (actA) NUMPV(q0a, qrfA, yaccA, lastA);

        __syncthreads();   // next tile resident; buf[cur] reusable
        cur ^= 1;
    }

    // den reduction: lanes l15, +16, +32, +48 hold disjoint key subsets of q-row l15
    float denA = daccA0 + daccA1, denB = daccB0 + daccB1;
    denA += __shfl_xor(denA, 16, 64);
    denA += __shfl_xor(denA, 32, 64);
    denB += __shfl_xor(denB, 16, 64);
    denB += __shfl_xor(denB, 32, 64);

    const int b = bh >> 4, h = bh & 15;
#pragma unroll
    for (int r = 0; r < 4; r++) {
        float drA = __shfl(denA, lg * 4 + r, 64);   // den of q-row lg*4+r (within wave strip)
        float drB = __shfl(denB, lg * 4 + r, 64);
        float invA = 1.f / drA;
        float invB = 1.f / drB;
        int rowA = q0a + w * 16 + lg * 4 + r;
        int rowB = q0b + w * 16 + lg * 4 + r;
#pragma unroll
        for (int nt2 = 0; nt2 < 4; nt2++) {
            y[((size_t)b * CC + rowA) * DD + h * DHH + nt2 * 16 + l15] = f2bf(yaccA[nt2][r] * invA);
            y[((size_t)b * CC + rowB) * DD + h * DHH + nt2 * 16 + l15] = f2bf(yaccB[nt2][r] * invB);
        }
    }
#undef STAGE
#undef NUMPV
}

// ---------------- output projection ----------------
__global__ __launch_bounds__(256) void out_proj_mfma_k(const ushort* __restrict__ yb,
                                                       const ushort* __restrict__ wob,
                                                       const float* __restrict__ bias,
                                                       float* __restrict__ out) {
    __shared__ ushort Al[128 * 64];
    __shared__ ushort Bl[128 * 64];
    const int tid = threadIdx.x;
    const int w = tid >> 6, l = tid & 63;
    const int l15 = l & 15, lg = l >> 4;
    const int wr = w >> 1, wc = w & 1;
    const int m0 = blockIdx.x * 128, n0 = blockIdx.y * 128;
    const int lrow = l >> 3, lch = l & 7;

    f32x4 acc[4][4];
#pragma unroll
    for (int i = 0; i < 4; i++)
#pragma unroll
        for (int j = 0; j < 4; j++) acc[i][j] = (f32x4){0.f, 0.f, 0.f, 0.f};

    for (int k0 = 0; k0 < 1024; k0 += 64) {
        __syncthreads();
#pragma unroll
        for (int c = 0; c < 4; c++) {
            int row = w * 32 + c * 8 + lrow;
            int gch = (lch ^ (row & 7)) * 8;
            gload16(yb + (size_t)(m0 + row) * 1024 + k0 + gch, &Al[(w * 32 + c * 8) * 64]);
            gload16(wob + (size_t)(n0 + row) * 1024 + k0 + gch, &Bl[(w * 32 + c * 8) * 64]);
        }
        __syncthreads();
#pragma unroll
        for (int kk = 0; kk < 2; kk++) {
            bf16x8 a[4], b[4];
#pragma unroll
            for (int mt = 0; mt < 4; mt++) {
                int row = wr * 64 + mt * 16 + l15;
                a[mt] = *reinterpret_cast<const bf16x8*>(&Al[row * 64 + ((kk * 4 + lg) ^ (row & 7)) * 8]);
            }
#pragma unroll
            for (int nt = 0; nt < 4; nt++) {
                int row = wc * 64 + nt * 16 + l15;
                b[nt] = *reinterpret_cast<const bf16x8*>(&Bl[row * 64 + ((kk * 4 + lg) ^ (row & 7)) * 8]);
            }
#pragma unroll
            for (int mt = 0; mt < 4; mt++)
#pragma unroll
                for (int nt = 0; nt < 4; nt++)
                    acc[mt][nt] = __builtin_amdgcn_mfma_f32_16x16x32_bf16(a[mt], b[nt], acc[mt][nt], 0, 0, 0);
        }
    }
#pragma unroll
    for (int mt = 0; mt < 4; mt++)
#pragma unroll
        for (int nt = 0; nt < 4; nt++) {
            int n = n0 + wc * 64 + nt * 16 + l15;
            float bv = bias[n];
#pragma unroll
            for (int r = 0; r < 4; r++) {
                int m = m0 + wr * 64 + mt * 16 + lg * 4 + r;
                out[(size_t)m * 1024 + n] = acc[mt][nt][r] + bv;
            }
        }
}

extern "C" void kernel_launch(void* const* d_in, const int* in_sizes, int n_in,
                              void* d_out, int out_size, void* d_ws, size_t ws_size,
                              hipStream_t stream) {
    (void)in_sizes; (void)n_in; (void)out_size; (void)ws_size;
    const float* x     = (const float*)d_in[0];
    const float* w_qkv = (const float*)d_in[1];
    const float* w_out = (const float*)d_in[2];
    const float* b_out = (const float*)d_in[3];
    float* out = (float*)d_out;

    char* p = (char*)d_ws;
    float* ct = (float*)p;  p += (size_t)CC * HALF * 4;
    float* st = (float*)p;  p += (size_t)CC * HALF * 4;
    ushort* xb  = (ushort*)p; p += (size_t)4096 * 1024 * 2;
    ushort* wqb = (ushort*)p; p += (size_t)3072 * 1024 * 2;
    ushort* wob = (ushort*)p; p += (size_t)1024 * 1024 * 2;
    const size_t TEN = (size_t)BB * HH * CC * DHH;  // 4,194,304
    ushort* qb = (ushort*)p; p += TEN * 2;
    ushort* kb = (ushort*)p; p += TEN * 2;
    ushort* vT = (ushort*)p; p += TEN * 2;
    ushort* qr = (ushort*)p; p += TEN * 2;
    ushort* kr = (ushort*)p; p += TEN * 2;
    ushort* yb = (ushort*)p; p += (size_t)4096 * 1024 * 2;

    cast3_rope_k<<<dim3(4352), dim3(256), 0, stream>>>(x, w_qkv, w_out, xb, wqb, wob, ct, st);
    qkv_gemm_mfma_k<<<dim3(32, 24), dim3(256), 0, stream>>>(xb, wqb, ct, st, qb, kb, qr, kr, vT);
    attn_fused_k<<<dim3(512), dim3(256), 0, stream>>>(vT, qb, kb, qr, kr, yb);
    out_proj_mfma_k<<<dim3(32, 8), dim3(256), 0, stream>>>(yb, wob, b_out, out);
}